// Round 3
// baseline (233.216 us; speedup 1.0000x reference)
//
#include <hip/hip_runtime.h>

// Problem dims (fixed by the reference)
#define BSZ 32
#define SEQ 512
#define LW  16      // chars per word (max)
#define GD  300     // glove dim
#define CEM 64      // char emb dim
#define OD  100     // out dim of conv/linear
#define NW  (BSZ * SEQ)   // 16384 words
#define WPB 16      // words per block (4 waves x 4 words)
#define WCN (CEM * OD + OD)   // 6500 useful floats in Wc
#define WCPAD 6656            // padded to 1664 float4 for staging

// Wc layout in d_ws: [0 .. 6400) = W[e][o] row-major, [6400 .. 6500) = c[o]
//   W[e][o] = sum_j lin_w[o,j] * conv_w[j,e]
//   c[o]    = lin_b[o] + sum_j lin_w[o,j] * conv_b[j]
__global__ __launch_bounds__(128) void precompute_Wc(
        const float* __restrict__ conv_w, const float* __restrict__ conv_b,
        const float* __restrict__ lin_w,  const float* __restrict__ lin_b,
        float* __restrict__ Wc) {
    const int o = threadIdx.x;
    if (o >= OD) return;
    const int e = blockIdx.x;
    const float* lw = lin_w + o * OD;
    if (e < CEM) {
        float a0 = 0.f, a1 = 0.f, a2 = 0.f, a3 = 0.f;
        #pragma unroll 5
        for (int j = 0; j < OD; j += 4) {
            a0 = fmaf(lw[j + 0], conv_w[(j + 0) * CEM + e], a0);
            a1 = fmaf(lw[j + 1], conv_w[(j + 1) * CEM + e], a1);
            a2 = fmaf(lw[j + 2], conv_w[(j + 2) * CEM + e], a2);
            a3 = fmaf(lw[j + 3], conv_w[(j + 3) * CEM + e], a3);
        }
        Wc[e * OD + o] = (a0 + a1) + (a2 + a3);
    } else {
        float a0 = lin_b[o], a1 = 0.f, a2 = 0.f, a3 = 0.f;
        #pragma unroll 5
        for (int j = 0; j < OD; j += 4) {
            a0 = fmaf(lw[j + 0], conv_b[j + 0], a0);
            a1 = fmaf(lw[j + 1], conv_b[j + 1], a1);
            a2 = fmaf(lw[j + 2], conv_b[j + 2], a2);
            a3 = fmaf(lw[j + 3], conv_b[j + 3], a3);
        }
        Wc[CEM * OD + o] = (a0 + a1) + (a2 + a3);
    }
}

// 16 words per block: 4 waves x 4 words each. Wc staged in LDS once per block.
__global__ __launch_bounds__(256, 4) void fused_embed(
        const int*   __restrict__ word_tokens,
        const int*   __restrict__ char_ids,
        const int*   __restrict__ char_lens,
        const float* __restrict__ glove,
        const float* __restrict__ char_table,
        const float* __restrict__ Wc,
        float*       __restrict__ out) {
    __shared__ float WcS[WCPAD];
    __shared__ float Means[WPB][CEM];

    const int tid  = threadIdx.x;
    const int wave = tid >> 6;
    const int lane = tid & 63;

    // ---- stage Wc -> LDS (once per block, coalesced float4) ----
    {
        const float4* src = (const float4*)Wc;
        float4*       dst = (float4*)WcS;
        #pragma unroll
        for (int i = tid; i < WCPAD / 4; i += 256)
            dst[i] = src[i];
    }
    __syncthreads();

    const int word0 = blockIdx.x * WPB + wave * 4;

    // ---- phase 1: per wave, 4 words: glove copy + masked char mean ----
    #pragma unroll
    for (int k = 0; k < 4; ++k) {
        const int word = word0 + k;
        const int tok = word_tokens[word];          // wave-uniform (s_load)
        const int len = char_lens[word];

        const int4* cid4 = (const int4*)(char_ids + (size_t)word * LW);
        int4 c0 = cid4[0], c1 = cid4[1], c2 = cid4[2], c3 = cid4[3];

        const float4* g4 = (const float4*)(glove + (size_t)tok * GD);
        float4 g0 = g4[lane];
        float4 g1;
        const bool tail = lane < (GD / 4 - 64);     // lanes 0..10
        if (tail) g1 = g4[64 + lane];

        const int ids[LW] = {c0.x, c0.y, c0.z, c0.w, c1.x, c1.y, c1.z, c1.w,
                             c2.x, c2.y, c2.z, c2.w, c3.x, c3.y, c3.z, c3.w};
        float a0 = 0.f, a1 = 0.f, a2 = 0.f, a3 = 0.f;
        #pragma unroll
        for (int l = 0; l < LW; l += 4) {
            float v0 = char_table[ids[l + 0] * CEM + lane];  // L1-resident rows
            float v1 = char_table[ids[l + 1] * CEM + lane];
            float v2 = char_table[ids[l + 2] * CEM + lane];
            float v3 = char_table[ids[l + 3] * CEM + lane];
            a0 += (l + 0 < len) ? v0 : 0.f;
            a1 += (l + 1 < len) ? v1 : 0.f;
            a2 += (l + 2 < len) ? v2 : 0.f;
            a3 += (l + 3 < len) ? v3 : 0.f;
        }

        float4* d4 = (float4*)(out + (size_t)word * (GD + OD));
        d4[lane] = g0;
        if (tail) d4[64 + lane] = g1;

        Means[wave * 4 + k][lane] = ((a0 + a1) + (a2 + a3)) * (1.f / (float)len);
    }
    // No second sync: each wave reads only its own Means rows (+ WcS, synced above).

    // ---- phase 2: batched matvec, W reads shared across 4 words ----
    const float* cS = WcS + CEM * OD;
    const float cl = cS[lane];
    const float ch = (lane < OD - 64) ? cS[64 + lane] : 0.f;
    float s0[4] = {cl, cl, cl, cl};
    float s1[4] = {ch, ch, ch, ch};

    const float4* M0 = (const float4*)Means[wave * 4 + 0];
    const float4* M1 = (const float4*)Means[wave * 4 + 1];
    const float4* M2 = (const float4*)Means[wave * 4 + 2];
    const float4* M3 = (const float4*)Means[wave * 4 + 3];

    #pragma unroll
    for (int e4 = 0; e4 < CEM / 4; ++e4) {
        float4 mv0 = M0[e4], mv1 = M1[e4], mv2 = M2[e4], mv3 = M3[e4];
        float m0[4] = {mv0.x, mv0.y, mv0.z, mv0.w};
        float m1[4] = {mv1.x, mv1.y, mv1.z, mv1.w};
        float m2[4] = {mv2.x, mv2.y, mv2.z, mv2.w};
        float m3[4] = {mv3.x, mv3.y, mv3.z, mv3.w};
        #pragma unroll
        for (int t = 0; t < 4; ++t) {
            const int e = e4 * 4 + t;
            const float wlo = WcS[e * OD + lane];        // conflict-free b32
            const float whi = WcS[e * OD + 64 + lane];   // max 6427 < 6500
            s0[0] = fmaf(m0[t], wlo, s0[0]);  s1[0] = fmaf(m0[t], whi, s1[0]);
            s0[1] = fmaf(m1[t], wlo, s0[1]);  s1[1] = fmaf(m1[t], whi, s1[1]);
            s0[2] = fmaf(m2[t], wlo, s0[2]);  s1[2] = fmaf(m2[t], whi, s1[2]);
            s0[3] = fmaf(m3[t], wlo, s0[3]);  s1[3] = fmaf(m3[t], whi, s1[3]);
        }
    }

    #pragma unroll
    for (int k = 0; k < 4; ++k) {
        float* co = out + (size_t)(word0 + k) * (GD + OD) + GD;
        co[lane] = s0[k];
        if (lane < OD - 64) co[64 + lane] = s1[k];
    }
}

extern "C" void kernel_launch(void* const* d_in, const int* in_sizes, int n_in,
                              void* d_out, int out_size, void* d_ws, size_t ws_size,
                              hipStream_t stream) {
    const int*   word_tokens = (const int*)  d_in[0];
    const int*   char_ids    = (const int*)  d_in[1];
    const int*   char_lens   = (const int*)  d_in[2];
    const float* glove       = (const float*)d_in[3];
    const float* char_table  = (const float*)d_in[4];
    const float* conv_w      = (const float*)d_in[5];
    const float* conv_b      = (const float*)d_in[6];
    const float* lin_w       = (const float*)d_in[7];
    const float* lin_b       = (const float*)d_in[8];
    float* out = (float*)d_out;
    float* Wc  = (float*)d_ws;   // uses 6500 floats; stage reads 6656 (pad junk unused)

    precompute_Wc<<<CEM + 1, 128, 0, stream>>>(conv_w, conv_b, lin_w, lin_b, Wc);

    fused_embed<<<NW / WPB, 256, 0, stream>>>(
        word_tokens, char_ids, char_lens, glove, char_table, Wc, out);
}

// Round 4
// 27.284 us; speedup vs baseline: 8.5476x; 8.5476x over previous
//
#include <hip/hip_runtime.h>

// Problem dims (fixed by the reference)
#define BSZ 32
#define SEQ 512
#define LW  16      // chars per word (max)
#define GD  300     // glove dim
#define CEM 64      // char emb dim
#define OD  100     // out dim of conv/linear
#define NW  (BSZ * SEQ)   // 16384 words
#define WPB 16      // words per block (4 waves x 4 words)

// Wc layout in d_ws: [0 .. 6400) = W[e][o] row-major, [6400 .. 6500) = c[o]
//   W[e][o] = sum_j lin_w[o,j] * conv_w[j,e]
//   c[o]    = lin_b[o] + sum_j lin_w[o,j] * conv_b[j]
__global__ __launch_bounds__(128) void precompute_Wc(
        const float* __restrict__ conv_w, const float* __restrict__ conv_b,
        const float* __restrict__ lin_w,  const float* __restrict__ lin_b,
        float* __restrict__ Wc) {
    const int o = threadIdx.x;
    if (o >= OD) return;
    const int e = blockIdx.x;
    const float* lw = lin_w + o * OD;
    if (e < CEM) {
        float a0 = 0.f, a1 = 0.f, a2 = 0.f, a3 = 0.f;
        #pragma unroll 5
        for (int j = 0; j < OD; j += 4) {
            a0 = fmaf(lw[j + 0], conv_w[(j + 0) * CEM + e], a0);
            a1 = fmaf(lw[j + 1], conv_w[(j + 1) * CEM + e], a1);
            a2 = fmaf(lw[j + 2], conv_w[(j + 2) * CEM + e], a2);
            a3 = fmaf(lw[j + 3], conv_w[(j + 3) * CEM + e], a3);
        }
        Wc[e * OD + o] = (a0 + a1) + (a2 + a3);
    } else {
        float a0 = lin_b[o], a1 = 0.f, a2 = 0.f, a3 = 0.f;
        #pragma unroll 5
        for (int j = 0; j < OD; j += 4) {
            a0 = fmaf(lw[j + 0], conv_b[j + 0], a0);
            a1 = fmaf(lw[j + 1], conv_b[j + 1], a1);
            a2 = fmaf(lw[j + 2], conv_b[j + 2], a2);
            a3 = fmaf(lw[j + 3], conv_b[j + 3], a3);
        }
        Wc[CEM * OD + o] = (a0 + a1) + (a2 + a3);
    }
}

// 16 words per block: 4 waves x 4 words each.
// Phase 1: gather (unroll 2 -> no spill). Phase 2: matvec with W reads
// (L1/L2-resident 26 KB table) shared across the wave's 4 words.
// No __syncthreads: each wave reads only its own Means rows.
__global__ __launch_bounds__(256) void fused_embed(
        const int*   __restrict__ word_tokens,
        const int*   __restrict__ char_ids,
        const int*   __restrict__ char_lens,
        const float* __restrict__ glove,
        const float* __restrict__ char_table,
        const float* __restrict__ Wc,
        float*       __restrict__ out) {
    __shared__ float Means[WPB][CEM];   // 4 KB

    const int wave = threadIdx.x >> 6;
    const int lane = threadIdx.x & 63;
    const int word0 = blockIdx.x * WPB + wave * 4;

    // ---- phase 1: 4 words per wave, at most 2 words' state live ----
    #pragma unroll 2
    for (int k = 0; k < 4; ++k) {
        const int word = word0 + k;
        const int tok = word_tokens[word];          // wave-uniform
        const int len = char_lens[word];

        const int4* cid4 = (const int4*)(char_ids + (size_t)word * LW);
        int4 c0 = cid4[0], c1 = cid4[1], c2 = cid4[2], c3 = cid4[3];

        const float4* g4 = (const float4*)(glove + (size_t)tok * GD);
        float4 g0 = g4[lane];
        float4 g1;
        const bool tail = lane < (GD / 4 - 64);     // lanes 0..10
        if (tail) g1 = g4[64 + lane];

        const int ids[LW] = {c0.x, c0.y, c0.z, c0.w, c1.x, c1.y, c1.z, c1.w,
                             c2.x, c2.y, c2.z, c2.w, c3.x, c3.y, c3.z, c3.w};
        float a0 = 0.f, a1 = 0.f, a2 = 0.f, a3 = 0.f;
        #pragma unroll
        for (int l = 0; l < LW; l += 4) {
            float v0 = char_table[ids[l + 0] * CEM + lane];  // L1/L2-resident rows
            float v1 = char_table[ids[l + 1] * CEM + lane];
            float v2 = char_table[ids[l + 2] * CEM + lane];
            float v3 = char_table[ids[l + 3] * CEM + lane];
            a0 += (l + 0 < len) ? v0 : 0.f;
            a1 += (l + 1 < len) ? v1 : 0.f;
            a2 += (l + 2 < len) ? v2 : 0.f;
            a3 += (l + 3 < len) ? v3 : 0.f;
        }

        float4* d4 = (float4*)(out + (size_t)word * (GD + OD));
        d4[lane] = g0;
        if (tail) d4[64 + lane] = g1;

        Means[wave * 4 + k][lane] = ((a0 + a1) + (a2 + a3)) * (1.f / (float)len);
    }

    // ---- phase 2: batched matvec, W loads shared across 4 words ----
    const float cl = Wc[CEM * OD + lane];                         // c[lane]
    const float ch = (lane < OD - 64) ? Wc[CEM * OD + 64 + lane] : 0.f;
    float s0[4] = {cl, cl, cl, cl};
    float s1[4] = {ch, ch, ch, ch};

    const float4* M0 = (const float4*)Means[wave * 4 + 0];
    const float4* M1 = (const float4*)Means[wave * 4 + 1];
    const float4* M2 = (const float4*)Means[wave * 4 + 2];
    const float4* M3 = (const float4*)Means[wave * 4 + 3];

    #pragma unroll 4
    for (int e4 = 0; e4 < CEM / 4; ++e4) {
        float4 mv0 = M0[e4], mv1 = M1[e4], mv2 = M2[e4], mv3 = M3[e4];  // LDS broadcast
        float m0[4] = {mv0.x, mv0.y, mv0.z, mv0.w};
        float m1[4] = {mv1.x, mv1.y, mv1.z, mv1.w};
        float m2[4] = {mv2.x, mv2.y, mv2.z, mv2.w};
        float m3[4] = {mv3.x, mv3.y, mv3.z, mv3.w};
        #pragma unroll
        for (int t = 0; t < 4; ++t) {
            const int e = e4 * 4 + t;
            const float wlo = Wc[e * OD + lane];        // coalesced, L1-resident
            const float whi = Wc[e * OD + 64 + lane];   // max idx 6427 < 6500
            s0[0] = fmaf(m0[t], wlo, s0[0]);  s1[0] = fmaf(m0[t], whi, s1[0]);
            s0[1] = fmaf(m1[t], wlo, s0[1]);  s1[1] = fmaf(m1[t], whi, s1[1]);
            s0[2] = fmaf(m2[t], wlo, s0[2]);  s1[2] = fmaf(m2[t], whi, s1[2]);
            s0[3] = fmaf(m3[t], wlo, s0[3]);  s1[3] = fmaf(m3[t], whi, s1[3]);
        }
    }

    #pragma unroll
    for (int k = 0; k < 4; ++k) {
        float* co = out + (size_t)(word0 + k) * (GD + OD) + GD;
        co[lane] = s0[k];
        if (lane < OD - 64) co[64 + lane] = s1[k];
    }
}

extern "C" void kernel_launch(void* const* d_in, const int* in_sizes, int n_in,
                              void* d_out, int out_size, void* d_ws, size_t ws_size,
                              hipStream_t stream) {
    const int*   word_tokens = (const int*)  d_in[0];
    const int*   char_ids    = (const int*)  d_in[1];
    const int*   char_lens   = (const int*)  d_in[2];
    const float* glove       = (const float*)d_in[3];
    const float* char_table  = (const float*)d_in[4];
    const float* conv_w      = (const float*)d_in[5];
    const float* conv_b      = (const float*)d_in[6];
    const float* lin_w       = (const float*)d_in[7];
    const float* lin_b       = (const float*)d_in[8];
    float* out = (float*)d_out;
    float* Wc  = (float*)d_ws;   // 6500 floats = 26 KB scratch

    precompute_Wc<<<CEM + 1, 128, 0, stream>>>(conv_w, conv_b, lin_w, lin_b, Wc);

    fused_embed<<<NW / WPB, 256, 0, stream>>>(
        word_tokens, char_ids, char_lens, glove, char_table, Wc, out);
}

// Round 5
// 22.277 us; speedup vs baseline: 10.4690x; 1.2248x over previous
//
#include <hip/hip_runtime.h>

// Problem dims (fixed by the reference)
#define LW   16      // chars per word (max)
#define GD   300     // glove dim
#define CEM  64      // char emb dim
#define OD   100     // out dim of conv/linear
#define NCH  128     // char vocab
#define NW   (32 * 512)   // 16384 words

// d_ws layout: T[128][100] at [0 .. 12800), c[100] at [12800 .. 12900)
//   T[ch][o] = sum_j lin_w[o,j] * (sum_e conv_w[j,e] * char_table[ch,e])
//   c[o]     = lin_b[o] + sum_j lin_w[o,j] * conv_b[j]
// One block per char. Step1: U[j] = conv(char ch). Step2: T row = lin_w @ U.
__global__ __launch_bounds__(128) void precompute_T(
        const float* __restrict__ char_table, const float* __restrict__ conv_w,
        const float* __restrict__ conv_b,     const float* __restrict__ lin_w,
        const float* __restrict__ lin_b,      float* __restrict__ ws) {
    __shared__ float ceS[CEM];
    __shared__ float U[OD];
    const int t  = threadIdx.x;
    const int ch = blockIdx.x;

    if (t < CEM) ceS[t] = char_table[ch * CEM + t];
    __syncthreads();

    if (t < OD) {
        const float* cw = conv_w + t * CEM;
        float a0 = 0.f, a1 = 0.f, a2 = 0.f, a3 = 0.f;
        #pragma unroll
        for (int e = 0; e < CEM; e += 4) {
            a0 = fmaf(cw[e + 0], ceS[e + 0], a0);   // ceS broadcast, conv_w L1-resident
            a1 = fmaf(cw[e + 1], ceS[e + 1], a1);
            a2 = fmaf(cw[e + 2], ceS[e + 2], a2);
            a3 = fmaf(cw[e + 3], ceS[e + 3], a3);
        }
        U[t] = (a0 + a1) + (a2 + a3);
    }
    __syncthreads();

    if (t < OD) {
        const float* lw = lin_w + t * OD;
        float a0 = 0.f, a1 = 0.f, a2 = 0.f, a3 = 0.f;
        #pragma unroll 5
        for (int j = 0; j < OD; j += 4) {
            a0 = fmaf(lw[j + 0], U[j + 0], a0);     // U broadcast
            a1 = fmaf(lw[j + 1], U[j + 1], a1);
            a2 = fmaf(lw[j + 2], U[j + 2], a2);
            a3 = fmaf(lw[j + 3], U[j + 3], a3);
        }
        ws[ch * OD + t] = (a0 + a1) + (a2 + a3);    // coalesced T row

        if (ch == 0) {                              // bias c, once
            float b0 = lin_b[t], b1 = 0.f, b2 = 0.f, b3 = 0.f;
            #pragma unroll 5
            for (int j = 0; j < OD; j += 4) {
                b0 = fmaf(lw[j + 0], conv_b[j + 0], b0);
                b1 = fmaf(lw[j + 1], conv_b[j + 1], b1);
                b2 = fmaf(lw[j + 2], conv_b[j + 2], b2);
                b3 = fmaf(lw[j + 3], conv_b[j + 3], b3);
            }
            ws[NCH * OD + t] = (b0 + b1) + (b2 + b3);
        }
    }
}

// One wave per word, 4 waves/block. char path = masked mean of T rows + c.
// Char-id groups use STATIC int4 components (no runtime-indexed array -> no scratch).
__global__ __launch_bounds__(256) void fused_embed(
        const int*   __restrict__ word_tokens,
        const int*   __restrict__ char_ids,
        const int*   __restrict__ char_lens,
        const float* __restrict__ glove,
        const float* __restrict__ ws,
        float*       __restrict__ out) {
    const int wave = threadIdx.x >> 6;
    const int lane = threadIdx.x & 63;
    const int word = blockIdx.x * 4 + wave;

    const int tok = word_tokens[word];              // wave-uniform
    const int len = char_lens[word];                // wave-uniform, >= 1

    const int4* cid4 = (const int4*)(char_ids + (size_t)word * LW);
    const int4 i0 = cid4[0], i1 = cid4[1], i2 = cid4[2], i3 = cid4[3];

    // glove passthrough: 75 float4, coalesced
    const float4* g4 = (const float4*)(glove + (size_t)tok * GD);
    float4 g0 = g4[lane];
    float4 g1;
    const bool tail = lane < (GD / 4 - 64);         // lanes 0..10
    if (tail) g1 = g4[64 + lane];
    float4* d4 = (float4*)(out + (size_t)word * (GD + OD));
    d4[lane] = g0;
    if (tail) d4[64 + lane] = g1;

    // bias (load early, hides under gather)
    const float cl = ws[NCH * OD + lane];                          // c[lane]
    const bool hi = lane < (OD - 64);                              // lanes 0..35
    const float chv = ws[NCH * OD + 64 + lane];                    // junk if !hi, masked later
    float acc0 = 0.f, acc1 = 0.f;

    // masked mean of T rows; 4-char groups, wave-uniform early-out.
    // T row loads: 64+64 consecutive lanes, L1/L2-resident (51 KB table).
    // hi-part reads T[ch*100+64+lane]; max idx 12827 < 12900 (in d_ws) -> safe, masked.
#define CGROUP(iv, base)                                                   \
    {                                                                      \
        const float* t0 = ws + (iv).x * OD;                                \
        const float* t1 = ws + (iv).y * OD;                                \
        const float* t2 = ws + (iv).z * OD;                                \
        const float* t3 = ws + (iv).w * OD;                                \
        float v0 = t0[lane], w0 = t0[64 + lane];                           \
        float v1 = t1[lane], w1 = t1[64 + lane];                           \
        float v2 = t2[lane], w2 = t2[64 + lane];                           \
        float v3 = t3[lane], w3 = t3[64 + lane];                           \
        acc0 += ((base) + 0 < len) ? v0 : 0.f;                             \
        acc1 += ((base) + 0 < len) ? w0 : 0.f;                             \
        acc0 += ((base) + 1 < len) ? v1 : 0.f;                             \
        acc1 += ((base) + 1 < len) ? w1 : 0.f;                             \
        acc0 += ((base) + 2 < len) ? v2 : 0.f;                             \
        acc1 += ((base) + 2 < len) ? w2 : 0.f;                             \
        acc0 += ((base) + 3 < len) ? v3 : 0.f;                             \
        acc1 += ((base) + 3 < len) ? w3 : 0.f;                             \
    }

    CGROUP(i0, 0)                       // len >= 1 always
    if (len > 4)  CGROUP(i1, 4)
    if (len > 8)  CGROUP(i2, 8)
    if (len > 12) CGROUP(i3, 12)
#undef CGROUP

    const float inv = 1.f / (float)len;
    float* co = out + (size_t)word * (GD + OD) + GD;
    co[lane] = fmaf(acc0, inv, cl);
    if (hi) co[64 + lane] = fmaf(acc1, inv, chv);
}

extern "C" void kernel_launch(void* const* d_in, const int* in_sizes, int n_in,
                              void* d_out, int out_size, void* d_ws, size_t ws_size,
                              hipStream_t stream) {
    const int*   word_tokens = (const int*)  d_in[0];
    const int*   char_ids    = (const int*)  d_in[1];
    const int*   char_lens   = (const int*)  d_in[2];
    const float* glove       = (const float*)d_in[3];
    const float* char_table  = (const float*)d_in[4];
    const float* conv_w      = (const float*)d_in[5];
    const float* conv_b      = (const float*)d_in[6];
    const float* lin_w       = (const float*)d_in[7];
    const float* lin_b       = (const float*)d_in[8];
    float* out = (float*)d_out;
    float* ws  = (float*)d_ws;   // needs 12928 floats ~= 51.7 KB

    precompute_T<<<NCH, 128, 0, stream>>>(char_table, conv_w, conv_b, lin_w, lin_b, ws);

    fused_embed<<<NW / 4, 256, 0, stream>>>(
        word_tokens, char_ids, char_lens, glove, ws, out);
}